// Round 11
// baseline (311.621 us; speedup 1.0000x reference)
//
#include <hip/hip_runtime.h>
#include <hip/hip_fp16.h>

#define N_NODES 65536
#define N_EDGES 1048576
#define F 128
#define NBUCK 256          // dst >> 8

typedef unsigned long long ull;
typedef _Float16 half8 __attribute__((ext_vector_type(8)));
typedef float floatx4 __attribute__((ext_vector_type(4)));

// ---------------- bucket partition ----------------

__global__ __launch_bounds__(256) void k_zero256(int* gcnt) {
    gcnt[threadIdx.x] = 0;
}

__global__ __launch_bounds__(256) void k_bcount(const int* __restrict__ dst,
                                                int* __restrict__ gcnt) {
    __shared__ int hist[NBUCK];
    int t = threadIdx.x;
    hist[t] = 0;
    __syncthreads();
    int base = blockIdx.x * 4096;
#pragma unroll
    for (int i = 0; i < 16; ++i) {
        int d = dst[base + i * 256 + t];
        atomicAdd(&hist[d >> 8], 1);
    }
    __syncthreads();
    atomicAdd(&gcnt[t], hist[t]);
}

__global__ __launch_bounds__(256) void k_bscan(const int* __restrict__ gcnt,
                                               int* __restrict__ boff,
                                               int* __restrict__ gfill) {
    __shared__ int s[256];
    int t = threadIdx.x;
    int v = gcnt[t];
    s[t] = v;
    __syncthreads();
    for (int off = 1; off < 256; off <<= 1) {
        int tv = (t >= off) ? s[t - off] : 0;
        __syncthreads();
        s[t] += tv;
        __syncthreads();
    }
    int excl = s[t] - v;
    boff[t] = excl;
    gfill[t] = excl;
    if (t == 255) boff[256] = N_EDGES;
}

// brec: ew(32) | dloc(8 @ bit16) | src(16)
__global__ __launch_bounds__(256) void k_bpart(const int* __restrict__ srcArr,
                                               const int* __restrict__ dstArr,
                                               const float* __restrict__ ew,
                                               int* __restrict__ gfill,
                                               ull* __restrict__ brec) {
    __shared__ int hist[NBUCK];
    __shared__ int cur[NBUCK];
    int t = threadIdx.x;
    hist[t] = 0;
    __syncthreads();
    int base = blockIdx.x * 4096;
    int dv[16];
#pragma unroll
    for (int i = 0; i < 16; ++i) {
        dv[i] = dstArr[base + i * 256 + t];
        atomicAdd(&hist[dv[i] >> 8], 1);
    }
    __syncthreads();
    cur[t] = atomicAdd(&gfill[t], hist[t]);
    __syncthreads();
#pragma unroll
    for (int i = 0; i < 16; ++i) {
        int e = base + i * 256 + t;
        int d = dv[i];
        unsigned int s = (unsigned int)srcArr[e];
        unsigned int wb = __float_as_uint(ew[e]);
        int pos = atomicAdd(&cur[d >> 8], 1);
        brec[pos] = ((ull)wb << 32) | ((ull)(d & 255) << 16) | (ull)s;
    }
}

// per-bucket CSR build (LDS hist: count<<40 | fixed-point ew-sum)
__global__ __launch_bounds__(256) void k_build(const ull* __restrict__ brec,
                                               const int* __restrict__ boff,
                                               float* __restrict__ dinv,
                                               int* __restrict__ row_ptr,
                                               ull* __restrict__ edge8) {
    __shared__ ull packed[256];
    __shared__ int sc[256];
    __shared__ int cur[256];
    int t = threadIdx.x;
    int b = blockIdx.x;
    packed[t] = 0ULL;
    __syncthreads();

    int beg = boff[b], end = boff[b + 1];
    for (int j = beg + t; j < end; j += 256) {
        ull r = brec[j];
        int dloc = (int)((r >> 16) & 255);
        float w = __uint_as_float((unsigned int)(r >> 32));
        ull fx = (ull)(w * 1073741824.0f);  // 2^30 fixed point
        atomicAdd(&packed[dloc], (1ULL << 40) | fx);
    }
    __syncthreads();

    ull p = packed[t];
    int c = (int)(p >> 40);
    float deg = 1.0f + (float)(p & ((1ULL << 40) - 1)) * (1.0f / 1073741824.0f);
    dinv[b * 256 + t] = rsqrtf(deg);

    sc[t] = c;
    __syncthreads();
    for (int off = 1; off < 256; off <<= 1) {
        int tv = (t >= off) ? sc[t - off] : 0;
        __syncthreads();
        sc[t] += tv;
        __syncthreads();
    }
    int excl = sc[t] - c;
    row_ptr[b * 256 + t] = beg + excl;
    if (b == NBUCK - 1 && t == 255) row_ptr[N_NODES] = N_EDGES;
    cur[t] = beg + excl;
    __syncthreads();

    for (int j = beg + t; j < end; j += 256) {
        ull r = brec[j];
        int dloc = (int)((r >> 16) & 255);
        int pos = atomicAdd(&cur[dloc], 1);
        edge8[pos] = (r & 0xFFFFFFFF00000000ULL) | (r & 0xFFFFULL);  // ew | src
    }
}

// coef' = dinv[src] * ew   (dinv[dst] folded into aggregate epilogue)
__global__ __launch_bounds__(256) void k_coef(ull* __restrict__ edge8,
                                              const float* __restrict__ dinv) {
    int e0 = (blockIdx.x * 256 + threadIdx.x) * 4;
#pragma unroll
    for (int i = 0; i < 4; ++i) {
        int e = e0 + i;
        ull r = edge8[e];
        int s = (int)(r & 0xFFFF);
        float w = __uint_as_float((unsigned int)(r >> 32));
        float c = dinv[s] * w;
        edge8[e] = ((ull)__float_as_uint(c) << 32) | (r & 0xFFFFULL);
    }
}

// ---------------- MFMA GEMM (fp32 A via hi/lo): H[4][N][32] fp16 = X fp32 @ W --
// Output SLICE-MAJOR, 4 slices of 32 features (64B rows). LDS repack epilogue.

__global__ __launch_bounds__(256) void k_gemm_mfma(const float* __restrict__ X,
                                                   const float* __restrict__ W,
                                                   __half* __restrict__ Y) {
    __shared__ __align__(16) char smem[40960];
    _Float16 (*Ah)[40] = (_Float16(*)[40])(smem);
    _Float16 (*Al)[40] = (_Float16(*)[40])(smem + 10240);
    _Float16 (*Bh)[40] = (_Float16(*)[40])(smem + 20480);
    _Float16 (*Bl)[40] = (_Float16(*)[40])(smem + 30720);

    const int tid = threadIdx.x;
    const int wv = tid >> 6;
    const int ln = tid & 63;
    const long rowbase = (long)blockIdx.x * 128;

    floatx4 acc[2][8];
#pragma unroll
    for (int i = 0; i < 2; ++i)
#pragma unroll
        for (int j = 0; j < 8; ++j) acc[i][j] = (floatx4)(0.f);

    for (int k0 = 0; k0 < 128; k0 += 32) {
        {
            int row = tid >> 1;
            int kh = (tid & 1) * 16;
            const float* src = &X[(rowbase + row) * 128 + k0 + kh];
            _Float16 hi[16], lo[16];
#pragma unroll
            for (int i = 0; i < 16; i += 4) {
                float4 v = *(const float4*)&src[i];
                hi[i + 0] = (_Float16)v.x; lo[i + 0] = (_Float16)(v.x - (float)hi[i + 0]);
                hi[i + 1] = (_Float16)v.y; lo[i + 1] = (_Float16)(v.y - (float)hi[i + 1]);
                hi[i + 2] = (_Float16)v.z; lo[i + 2] = (_Float16)(v.z - (float)hi[i + 2]);
                hi[i + 3] = (_Float16)v.w; lo[i + 3] = (_Float16)(v.w - (float)hi[i + 3]);
            }
            *(half8*)&Ah[row][kh] = *(half8*)&hi[0];
            *(half8*)&Ah[row][kh + 8] = *(half8*)&hi[8];
            *(half8*)&Al[row][kh] = *(half8*)&lo[0];
            *(half8*)&Al[row][kh + 8] = *(half8*)&lo[8];
        }
        {
            int n = tid & 127;
            int kh = (tid >> 7) * 16;
            _Float16 hi[16], lo[16];
#pragma unroll
            for (int i = 0; i < 16; ++i) {
                float v = W[(k0 + kh + i) * 128 + n];
                hi[i] = (_Float16)v;
                lo[i] = (_Float16)(v - (float)hi[i]);
            }
            *(half8*)&Bh[n][kh] = *(half8*)&hi[0];
            *(half8*)&Bh[n][kh + 8] = *(half8*)&hi[8];
            *(half8*)&Bl[n][kh] = *(half8*)&lo[0];
            *(half8*)&Bl[n][kh + 8] = *(half8*)&lo[8];
        }
        __syncthreads();

        int arow0 = wv * 32 + (ln & 15);
        int kq = (ln >> 4) * 8;
        half8 a_hi0 = *(const half8*)&Ah[arow0][kq];
        half8 a_hi1 = *(const half8*)&Ah[arow0 + 16][kq];
        half8 a_lo0 = *(const half8*)&Al[arow0][kq];
        half8 a_lo1 = *(const half8*)&Al[arow0 + 16][kq];
#pragma unroll
        for (int ct = 0; ct < 8; ++ct) {
            int bcol = ct * 16 + (ln & 15);
            half8 b_hi = *(const half8*)&Bh[bcol][kq];
            half8 b_lo = *(const half8*)&Bl[bcol][kq];
            acc[0][ct] = __builtin_amdgcn_mfma_f32_16x16x32_f16(a_hi0, b_hi, acc[0][ct], 0, 0, 0);
            acc[0][ct] = __builtin_amdgcn_mfma_f32_16x16x32_f16(a_hi0, b_lo, acc[0][ct], 0, 0, 0);
            acc[0][ct] = __builtin_amdgcn_mfma_f32_16x16x32_f16(a_lo0, b_hi, acc[0][ct], 0, 0, 0);
            acc[1][ct] = __builtin_amdgcn_mfma_f32_16x16x32_f16(a_hi1, b_hi, acc[1][ct], 0, 0, 0);
            acc[1][ct] = __builtin_amdgcn_mfma_f32_16x16x32_f16(a_hi1, b_lo, acc[1][ct], 0, 0, 0);
            acc[1][ct] = __builtin_amdgcn_mfma_f32_16x16x32_f16(a_lo1, b_hi, acc[1][ct], 0, 0, 0);
        }
        __syncthreads();
    }

    // repack via LDS, then slice-major (4 x 32-feature) contiguous stores
    _Float16 (*T)[132] = (_Float16(*)[132])smem;
#pragma unroll
    for (int rt = 0; rt < 2; ++rt)
#pragma unroll
        for (int ct = 0; ct < 8; ++ct)
#pragma unroll
            for (int reg = 0; reg < 4; ++reg)
                T[wv * 32 + rt * 16 + (ln >> 4) * 4 + reg][ct * 16 + (ln & 15)] =
                    (_Float16)acc[rt][ct][reg];
    __syncthreads();
    {
        int s = tid >> 6;            // slice 0..3
        int r0 = (tid & 63) * 2;     // 2 rows per thread
        char* dstB = (char*)Y + ((size_t)s * N_NODES + rowbase + r0) * 64;
#pragma unroll
        for (int i = 0; i < 2; ++i) {
            *(float4*)(dstB + i * 64 + 0)  = *(float4*)&T[r0 + i][s * 32 + 0];
            *(float4*)(dstB + i * 64 + 16) = *(float4*)&T[r0 + i][s * 32 + 8];
            *(float4*)(dstB + i * 64 + 32) = *(float4*)&T[r0 + i][s * 32 + 16];
            *(float4*)(dstB + i * 64 + 48) = *(float4*)&T[r0 + i][s * 32 + 24];
        }
    }
}

// ---------------- MFMA GEMM (fp16 slice-major A): H fp16 = X_s @ W ------------

__global__ __launch_bounds__(256) void k_gemm_mfma_h(const __half* __restrict__ X,
                                                     const float* __restrict__ W,
                                                     __half* __restrict__ Y) {
    __shared__ __align__(16) char smem[33792];
    _Float16 (*Ah)[40] = (_Float16(*)[40])(smem);
    _Float16 (*Bh)[40] = (_Float16(*)[40])(smem + 10240);
    _Float16 (*Bl)[40] = (_Float16(*)[40])(smem + 20480);

    const int tid = threadIdx.x;
    const int wv = tid >> 6;
    const int ln = tid & 63;
    const long rowbase = (long)blockIdx.x * 128;

    floatx4 acc[2][8];
#pragma unroll
    for (int i = 0; i < 2; ++i)
#pragma unroll
        for (int j = 0; j < 8; ++j) acc[i][j] = (floatx4)(0.f);

    for (int k0 = 0; k0 < 128; k0 += 32) {
        {
            int row = tid >> 1;
            int k = k0 + (tid & 1) * 16;
            int sl = k >> 5;
            int off = k & 31;
            const __half* src = &X[((size_t)sl * N_NODES + rowbase + row) * 32 + off];
            *(half8*)&Ah[row][(tid & 1) * 16]     = *(const half8*)&src[0];
            *(half8*)&Ah[row][(tid & 1) * 16 + 8] = *(const half8*)&src[8];
        }
        {
            int n = tid & 127;
            int kh = (tid >> 7) * 16;
            _Float16 hi[16], lo[16];
#pragma unroll
            for (int i = 0; i < 16; ++i) {
                float v = W[(k0 + kh + i) * 128 + n];
                hi[i] = (_Float16)v;
                lo[i] = (_Float16)(v - (float)hi[i]);
            }
            *(half8*)&Bh[n][kh] = *(half8*)&hi[0];
            *(half8*)&Bh[n][kh + 8] = *(half8*)&hi[8];
            *(half8*)&Bl[n][kh] = *(half8*)&lo[0];
            *(half8*)&Bl[n][kh + 8] = *(half8*)&lo[8];
        }
        __syncthreads();

        int arow0 = wv * 32 + (ln & 15);
        int kq = (ln >> 4) * 8;
        half8 a0 = *(const half8*)&Ah[arow0][kq];
        half8 a1 = *(const half8*)&Ah[arow0 + 16][kq];
#pragma unroll
        for (int ct = 0; ct < 8; ++ct) {
            int bcol = ct * 16 + (ln & 15);
            half8 b_hi = *(const half8*)&Bh[bcol][kq];
            half8 b_lo = *(const half8*)&Bl[bcol][kq];
            acc[0][ct] = __builtin_amdgcn_mfma_f32_16x16x32_f16(a0, b_hi, acc[0][ct], 0, 0, 0);
            acc[0][ct] = __builtin_amdgcn_mfma_f32_16x16x32_f16(a0, b_lo, acc[0][ct], 0, 0, 0);
            acc[1][ct] = __builtin_amdgcn_mfma_f32_16x16x32_f16(a1, b_hi, acc[1][ct], 0, 0, 0);
            acc[1][ct] = __builtin_amdgcn_mfma_f32_16x16x32_f16(a1, b_lo, acc[1][ct], 0, 0, 0);
        }
        __syncthreads();
    }

    _Float16 (*T)[132] = (_Float16(*)[132])smem;
#pragma unroll
    for (int rt = 0; rt < 2; ++rt)
#pragma unroll
        for (int ct = 0; ct < 8; ++ct)
#pragma unroll
            for (int reg = 0; reg < 4; ++reg)
                T[wv * 32 + rt * 16 + (ln >> 4) * 4 + reg][ct * 16 + (ln & 15)] =
                    (_Float16)acc[rt][ct][reg];
    __syncthreads();
    {
        int s = tid >> 6;
        int r0 = (tid & 63) * 2;
        char* dstB = (char*)Y + ((size_t)s * N_NODES + rowbase + r0) * 64;
#pragma unroll
        for (int i = 0; i < 2; ++i) {
            *(float4*)(dstB + i * 64 + 0)  = *(float4*)&T[r0 + i][s * 32 + 0];
            *(float4*)(dstB + i * 64 + 16) = *(float4*)&T[r0 + i][s * 32 + 8];
            *(float4*)(dstB + i * 64 + 32) = *(float4*)&T[r0 + i][s * 32 + 16];
            *(float4*)(dstB + i * 64 + 48) = *(float4*)&T[r0 + i][s * 32 + 24];
        }
    }
}

// ---------------- MFMA FC (fp16 slice-major A): out[Nx64] fp32 ----------------

__global__ __launch_bounds__(256) void k_fc_mfma_h(const __half* __restrict__ X,
                                                   const float* __restrict__ W,
                                                   const float* __restrict__ bias,
                                                   float* __restrict__ Y) {
    __shared__ _Float16 Ah[128][40];
    __shared__ _Float16 Bh[64][40];
    __shared__ _Float16 Bl[64][40];

    const int tid = threadIdx.x;
    const int wv = tid >> 6;
    const int ln = tid & 63;
    const long rowbase = (long)blockIdx.x * 128;

    floatx4 acc[2][4];
#pragma unroll
    for (int i = 0; i < 2; ++i)
#pragma unroll
        for (int j = 0; j < 4; ++j) acc[i][j] = (floatx4)(0.f);

    for (int k0 = 0; k0 < 128; k0 += 32) {
        {
            int row = tid >> 1;
            int k = k0 + (tid & 1) * 16;
            int sl = k >> 5;
            int off = k & 31;
            const __half* src = &X[((size_t)sl * N_NODES + rowbase + row) * 32 + off];
            *(half8*)&Ah[row][(tid & 1) * 16]     = *(const half8*)&src[0];
            *(half8*)&Ah[row][(tid & 1) * 16 + 8] = *(const half8*)&src[8];
        }
        {
            int n = tid & 63;
            int kh = (tid >> 6) * 8;   // 0,8,16,24
            _Float16 hi[8], lo[8];
#pragma unroll
            for (int i = 0; i < 8; ++i) {
                float v = W[(k0 + kh + i) * 64 + n];
                hi[i] = (_Float16)v;
                lo[i] = (_Float16)(v - (float)hi[i]);
            }
            *(half8*)&Bh[n][kh] = *(half8*)&hi[0];
            *(half8*)&Bl[n][kh] = *(half8*)&lo[0];
        }
        __syncthreads();

        int arow0 = wv * 32 + (ln & 15);
        int kq = (ln >> 4) * 8;
        half8 a0 = *(const half8*)&Ah[arow0][kq];
        half8 a1 = *(const half8*)&Ah[arow0 + 16][kq];
#pragma unroll
        for (int ct = 0; ct < 4; ++ct) {
            int bcol = ct * 16 + (ln & 15);
            half8 b_hi = *(const half8*)&Bh[bcol][kq];
            half8 b_lo = *(const half8*)&Bl[bcol][kq];
            acc[0][ct] = __builtin_amdgcn_mfma_f32_16x16x32_f16(a0, b_hi, acc[0][ct], 0, 0, 0);
            acc[0][ct] = __builtin_amdgcn_mfma_f32_16x16x32_f16(a0, b_lo, acc[0][ct], 0, 0, 0);
            acc[1][ct] = __builtin_amdgcn_mfma_f32_16x16x32_f16(a1, b_hi, acc[1][ct], 0, 0, 0);
            acc[1][ct] = __builtin_amdgcn_mfma_f32_16x16x32_f16(a1, b_lo, acc[1][ct], 0, 0, 0);
        }
        __syncthreads();
    }

#pragma unroll
    for (int rt = 0; rt < 2; ++rt)
#pragma unroll
        for (int ct = 0; ct < 4; ++ct)
#pragma unroll
            for (int reg = 0; reg < 4; ++reg) {
                long row = rowbase + wv * 32 + rt * 16 + (ln >> 4) * 4 + reg;
                int col = ct * 16 + (ln & 15);
                Y[row * 64 + col] = acc[rt][ct][reg] + bias[col];
            }
}

// ---------------- XCD-sliced aggregation, independent per-group node streams --
// slice = bid & 3 (XCD-pinned: xcd = bid%8 -> slice = xcd&3); slice = 4MB,
// ~L2-resident. Wave = 4 groups x 16 lanes. Each group owns 16 CONSECUTIVE
// nodes = one contiguous edge window [row_ptr[lo], row_ptr[lo+16]), streamed
// in 16-edge chunks: pass 1 issues 16 independent row-gathers (64B rows),
// pass 2 consumes with group-uniform node-boundary flushes. No lockstep
// across groups -> imbalance averages over ~256 edges.

__global__ __launch_bounds__(256) void k_aggregate_s(const __half2* __restrict__ H,
                                                     const int* __restrict__ row_ptr,
                                                     const ull* __restrict__ edge8,
                                                     const float* __restrict__ dinv,
                                                     const float* __restrict__ bias,
                                                     __half2* __restrict__ out) {
    const int tid = threadIdx.x;
    const int wv = tid >> 6;
    const int ln = tid & 63;
    const int g = ln >> 4;          // group 0..3
    const int li = ln & 15;         // lane in group
    const int s = blockIdx.x & 3;   // slice (XCD-pinned)
    const int nb = blockIdx.x >> 2;

    const __half2* Hs = H + (size_t)s * (N_NODES * 16);
    __half2* Os = out + (size_t)s * (N_NODES * 16);
    float2 bb = ((const float2*)bias)[s * 16 + li];
    const int gb = g << 4;

    const int node_lo = nb * 256 + wv * 64 + g * 16;
    const int node_hi = node_lo + 16;
    const int ebeg = row_ptr[node_lo];
    const int eend = row_ptr[node_hi];

    int cur = node_lo;
    int cur_end = row_ptr[cur + 1];
    float2 acc = make_float2(0.f, 0.f);

    for (int e0 = ebeg; e0 < eend; e0 += 16) {
        ull r = 0ULL;
        if (e0 + li < eend) r = __builtin_nontemporal_load(&edge8[e0 + li]);
        // pass 1: 16 independent gathers (tail gathers row 0 of slice, harmless)
        unsigned int fr[16];
#pragma unroll
        for (int j = 0; j < 16; ++j) {
            ull rj = __shfl(r, gb + j);
            fr[j] = *(const unsigned int*)&Hs[(size_t)(rj & 0xFFFF) * 16 + li];
        }
        // pass 2: consume with flushes at node boundaries
#pragma unroll
        for (int j = 0; j < 16; ++j) {
            int eidx = e0 + j;
            if (eidx >= eend) break;
            while (eidx >= cur_end) {
                float di = dinv[cur];
                float2 h0 = __half22float2(Hs[(size_t)cur * 16 + li]);
                float ox = fmaxf(fmaf(di, acc.x, fmaf(di * di, h0.x, bb.x)), 0.f);
                float oy = fmaxf(fmaf(di, acc.y, fmaf(di * di, h0.y, bb.y)), 0.f);
                Os[(size_t)cur * 16 + li] = __floats2half2_rn(ox, oy);
                acc = make_float2(0.f, 0.f);
                ++cur;
                cur_end = row_ptr[cur + 1];
            }
            ull rj = __shfl(r, gb + j);
            float c = __uint_as_float((unsigned int)(rj >> 32));
            float2 f = __half22float2(*(__half2*)&fr[j]);
            acc.x = fmaf(c, f.x, acc.x);
            acc.y = fmaf(c, f.y, acc.y);
        }
    }
    // trailing flushes (covers empty nodes too)
    while (cur < node_hi) {
        float di = dinv[cur];
        float2 h0 = __half22float2(Hs[(size_t)cur * 16 + li]);
        float ox = fmaxf(fmaf(di, acc.x, fmaf(di * di, h0.x, bb.x)), 0.f);
        float oy = fmaxf(fmaf(di, acc.y, fmaf(di * di, h0.y, bb.y)), 0.f);
        Os[(size_t)cur * 16 + li] = __floats2half2_rn(ox, oy);
        acc = make_float2(0.f, 0.f);
        ++cur;
        if (cur < node_hi) cur_end = row_ptr[cur + 1];
    }
}

// ---------------- launch ----------------

extern "C" void kernel_launch(void* const* d_in, const int* in_sizes, int n_in,
                              void* d_out, int out_size, void* d_ws, size_t ws_size,
                              hipStream_t stream) {
    const float* x   = (const float*)d_in[0];
    const int*   ei  = (const int*)d_in[1];
    const float* ew  = (const float*)d_in[2];
    const float* W1  = (const float*)d_in[4];
    const float* b1  = (const float*)d_in[5];
    const float* W2  = (const float*)d_in[6];
    const float* b2  = (const float*)d_in[7];
    const float* fcW = (const float*)d_in[8];
    const float* fcb = (const float*)d_in[9];
    float* out = (float*)d_out;

    const int* srcArr = ei;
    const int* dstArr = ei + N_EDGES;

    char* w = (char*)d_ws;
    int* gcnt = (int*)w;               w += 256 * 4;
    int* boff = (int*)w;               w += 257 * 4;
    int* gfill = (int*)w;              w += 256 * 4;
    w += 4;
    float* dinv = (float*)w;           w += (size_t)N_NODES * 4;
    int* row_ptr = (int*)w;            w += (size_t)(N_NODES + 64) * 4;
    ull* edge8 = (ull*)w;              w += (size_t)N_EDGES * 8;
    __half* bufH = (__half*)w;         w += (size_t)N_NODES * F * 2;  // h slice-major
    __half* bufB = (__half*)w;         w += (size_t)N_NODES * F * 2;  // agg slice-major
    ull* brec = (ull*)bufH;            // 8MB, dead before gemm1 writes bufH

    k_zero256<<<1, 256, 0, stream>>>(gcnt);
    k_bcount<<<N_EDGES / 4096, 256, 0, stream>>>(dstArr, gcnt);
    k_bscan<<<1, 256, 0, stream>>>(gcnt, boff, gfill);
    k_bpart<<<N_EDGES / 4096, 256, 0, stream>>>(srcArr, dstArr, ew, gfill, brec);
    k_build<<<NBUCK, 256, 0, stream>>>(brec, boff, dinv, row_ptr, edge8);
    k_coef<<<N_EDGES / 1024, 256, 0, stream>>>(edge8, dinv);

    // layer 1: H1 (slice-major fp16) = x @ W1
    k_gemm_mfma<<<512, 256, 0, stream>>>(x, W1, bufH);
    k_aggregate_s<<<1024, 256, 0, stream>>>((const __half2*)bufH, row_ptr, edge8,
                                            dinv, b1, (__half2*)bufB);
    // layer 2: H2 = agg1 @ W2
    k_gemm_mfma_h<<<512, 256, 0, stream>>>(bufB, W2, bufH);
    k_aggregate_s<<<1024, 256, 0, stream>>>((const __half2*)bufH, row_ptr, edge8,
                                            dinv, b2, (__half2*)bufB);
    // FC: out fp32 = agg2 @ fcW + fcb
    k_fc_mfma_h<<<512, 256, 0, stream>>>(bufB, fcW, fcb, out);
}

// Round 12
// 197.775 us; speedup vs baseline: 1.5756x; 1.5756x over previous
//
#include <hip/hip_runtime.h>
#include <hip/hip_fp16.h>

#define N_NODES 65536
#define N_EDGES 1048576
#define F 128
#define NBUCK 256          // dst >> 8

typedef unsigned long long ull;
typedef _Float16 half8 __attribute__((ext_vector_type(8)));
typedef float floatx4 __attribute__((ext_vector_type(4)));

// ---------------- bucket partition ----------------

__global__ __launch_bounds__(256) void k_bcount(const int* __restrict__ dst,
                                                int* __restrict__ gcnt) {
    __shared__ int hist[NBUCK];
    int t = threadIdx.x;
    hist[t] = 0;
    __syncthreads();
    int base = blockIdx.x * 4096;
#pragma unroll
    for (int i = 0; i < 16; ++i) {
        int d = dst[base + i * 256 + t];
        atomicAdd(&hist[d >> 8], 1);
    }
    __syncthreads();
    atomicAdd(&gcnt[t], hist[t]);
}

__global__ __launch_bounds__(256) void k_bscan(const int* __restrict__ gcnt,
                                               int* __restrict__ boff,
                                               int* __restrict__ gfill) {
    __shared__ int s[256];
    int t = threadIdx.x;
    int v = gcnt[t];
    s[t] = v;
    __syncthreads();
    for (int off = 1; off < 256; off <<= 1) {
        int tv = (t >= off) ? s[t - off] : 0;
        __syncthreads();
        s[t] += tv;
        __syncthreads();
    }
    int excl = s[t] - v;
    boff[t] = excl;
    gfill[t] = excl;
    if (t == 255) boff[256] = N_EDGES;
}

// brec: ew(32) | dloc(8 @ bit16) | src(16)
__global__ __launch_bounds__(256) void k_bpart(const int* __restrict__ srcArr,
                                               const int* __restrict__ dstArr,
                                               const float* __restrict__ ew,
                                               int* __restrict__ gfill,
                                               ull* __restrict__ brec) {
    __shared__ int hist[NBUCK];
    __shared__ int cur[NBUCK];
    int t = threadIdx.x;
    hist[t] = 0;
    __syncthreads();
    int base = blockIdx.x * 4096;
    int dv[16];
#pragma unroll
    for (int i = 0; i < 16; ++i) {
        dv[i] = dstArr[base + i * 256 + t];
        atomicAdd(&hist[dv[i] >> 8], 1);
    }
    __syncthreads();
    cur[t] = atomicAdd(&gfill[t], hist[t]);
    __syncthreads();
#pragma unroll
    for (int i = 0; i < 16; ++i) {
        int e = base + i * 256 + t;
        int d = dv[i];
        unsigned int s = (unsigned int)srcArr[e];
        unsigned int wb = __float_as_uint(ew[e]);
        int pos = atomicAdd(&cur[d >> 8], 1);
        brec[pos] = ((ull)wb << 32) | ((ull)(d & 255) << 16) | (ull)s;
    }
}

// per-bucket CSR build (LDS hist: count<<40 | fixed-point ew-sum)
__global__ __launch_bounds__(256) void k_build(const ull* __restrict__ brec,
                                               const int* __restrict__ boff,
                                               float* __restrict__ dinv,
                                               int* __restrict__ row_ptr,
                                               ull* __restrict__ edge8) {
    __shared__ ull packed[256];
    __shared__ int sc[256];
    __shared__ int cur[256];
    int t = threadIdx.x;
    int b = blockIdx.x;
    packed[t] = 0ULL;
    __syncthreads();

    int beg = boff[b], end = boff[b + 1];
    for (int j = beg + t; j < end; j += 256) {
        ull r = brec[j];
        int dloc = (int)((r >> 16) & 255);
        float w = __uint_as_float((unsigned int)(r >> 32));
        ull fx = (ull)(w * 1073741824.0f);  // 2^30 fixed point
        atomicAdd(&packed[dloc], (1ULL << 40) | fx);
    }
    __syncthreads();

    ull p = packed[t];
    int c = (int)(p >> 40);
    float deg = 1.0f + (float)(p & ((1ULL << 40) - 1)) * (1.0f / 1073741824.0f);
    dinv[b * 256 + t] = rsqrtf(deg);

    sc[t] = c;
    __syncthreads();
    for (int off = 1; off < 256; off <<= 1) {
        int tv = (t >= off) ? sc[t - off] : 0;
        __syncthreads();
        sc[t] += tv;
        __syncthreads();
    }
    int excl = sc[t] - c;
    row_ptr[b * 256 + t] = beg + excl;
    if (b == NBUCK - 1 && t == 255) row_ptr[N_NODES] = N_EDGES;
    cur[t] = beg + excl;
    __syncthreads();

    for (int j = beg + t; j < end; j += 256) {
        ull r = brec[j];
        int dloc = (int)((r >> 16) & 255);
        int pos = atomicAdd(&cur[dloc], 1);
        edge8[pos] = (r & 0xFFFFFFFF00000000ULL) | (r & 0xFFFFULL);  // ew | src
    }
}

// coef' = dinv[src] * ew   (dinv[dst] folded into aggregate epilogue)
__global__ __launch_bounds__(256) void k_coef(ull* __restrict__ edge8,
                                              const float* __restrict__ dinv) {
    int e0 = (blockIdx.x * 256 + threadIdx.x) * 4;
#pragma unroll
    for (int i = 0; i < 4; ++i) {
        int e = e0 + i;
        ull r = edge8[e];
        int s = (int)(r & 0xFFFF);
        float w = __uint_as_float((unsigned int)(r >> 32));
        float c = dinv[s] * w;
        edge8[e] = ((ull)__float_as_uint(c) << 32) | (r & 0xFFFFULL);
    }
}

// ---------------- MFMA GEMM (fp32 A via hi/lo): Y[Nx128] fp16 = X fp32 @ W ----

__global__ __launch_bounds__(256) void k_gemm_mfma(const float* __restrict__ X,
                                                   const float* __restrict__ W,
                                                   __half* __restrict__ Y) {
    __shared__ _Float16 Ah[128][40];
    __shared__ _Float16 Al[128][40];
    __shared__ _Float16 Bh[128][40];
    __shared__ _Float16 Bl[128][40];

    const int tid = threadIdx.x;
    const int wv = tid >> 6;
    const int ln = tid & 63;
    const long rowbase = (long)blockIdx.x * 128;

    floatx4 acc[2][8];
#pragma unroll
    for (int i = 0; i < 2; ++i)
#pragma unroll
        for (int j = 0; j < 8; ++j) acc[i][j] = (floatx4)(0.f);

    for (int k0 = 0; k0 < 128; k0 += 32) {
        {
            int row = tid >> 1;
            int kh = (tid & 1) * 16;
            const float* src = &X[(rowbase + row) * 128 + k0 + kh];
            _Float16 hi[16], lo[16];
#pragma unroll
            for (int i = 0; i < 16; i += 4) {
                float4 v = *(const float4*)&src[i];
                hi[i + 0] = (_Float16)v.x; lo[i + 0] = (_Float16)(v.x - (float)hi[i + 0]);
                hi[i + 1] = (_Float16)v.y; lo[i + 1] = (_Float16)(v.y - (float)hi[i + 1]);
                hi[i + 2] = (_Float16)v.z; lo[i + 2] = (_Float16)(v.z - (float)hi[i + 2]);
                hi[i + 3] = (_Float16)v.w; lo[i + 3] = (_Float16)(v.w - (float)hi[i + 3]);
            }
            *(half8*)&Ah[row][kh] = *(half8*)&hi[0];
            *(half8*)&Ah[row][kh + 8] = *(half8*)&hi[8];
            *(half8*)&Al[row][kh] = *(half8*)&lo[0];
            *(half8*)&Al[row][kh + 8] = *(half8*)&lo[8];
        }
        {
            int n = tid & 127;
            int kh = (tid >> 7) * 16;
            _Float16 hi[16], lo[16];
#pragma unroll
            for (int i = 0; i < 16; ++i) {
                float v = W[(k0 + kh + i) * 128 + n];
                hi[i] = (_Float16)v;
                lo[i] = (_Float16)(v - (float)hi[i]);
            }
            *(half8*)&Bh[n][kh] = *(half8*)&hi[0];
            *(half8*)&Bh[n][kh + 8] = *(half8*)&hi[8];
            *(half8*)&Bl[n][kh] = *(half8*)&lo[0];
            *(half8*)&Bl[n][kh + 8] = *(half8*)&lo[8];
        }
        __syncthreads();

        int arow0 = wv * 32 + (ln & 15);
        int kq = (ln >> 4) * 8;
        half8 a_hi0 = *(const half8*)&Ah[arow0][kq];
        half8 a_hi1 = *(const half8*)&Ah[arow0 + 16][kq];
        half8 a_lo0 = *(const half8*)&Al[arow0][kq];
        half8 a_lo1 = *(const half8*)&Al[arow0 + 16][kq];
#pragma unroll
        for (int ct = 0; ct < 8; ++ct) {
            int bcol = ct * 16 + (ln & 15);
            half8 b_hi = *(const half8*)&Bh[bcol][kq];
            half8 b_lo = *(const half8*)&Bl[bcol][kq];
            acc[0][ct] = __builtin_amdgcn_mfma_f32_16x16x32_f16(a_hi0, b_hi, acc[0][ct], 0, 0, 0);
            acc[0][ct] = __builtin_amdgcn_mfma_f32_16x16x32_f16(a_hi0, b_lo, acc[0][ct], 0, 0, 0);
            acc[0][ct] = __builtin_amdgcn_mfma_f32_16x16x32_f16(a_lo0, b_hi, acc[0][ct], 0, 0, 0);
            acc[1][ct] = __builtin_amdgcn_mfma_f32_16x16x32_f16(a_hi1, b_hi, acc[1][ct], 0, 0, 0);
            acc[1][ct] = __builtin_amdgcn_mfma_f32_16x16x32_f16(a_hi1, b_lo, acc[1][ct], 0, 0, 0);
            acc[1][ct] = __builtin_amdgcn_mfma_f32_16x16x32_f16(a_lo1, b_hi, acc[1][ct], 0, 0, 0);
        }
        __syncthreads();
    }

#pragma unroll
    for (int rt = 0; rt < 2; ++rt)
#pragma unroll
        for (int ct = 0; ct < 8; ++ct)
#pragma unroll
            for (int reg = 0; reg < 4; ++reg) {
                long row = rowbase + wv * 32 + rt * 16 + (ln >> 4) * 4 + reg;
                Y[row * 128 + ct * 16 + (ln & 15)] = __float2half(acc[rt][ct][reg]);
            }
}

// ---------------- MFMA GEMM (fp16 A, exact): Y[Nx128] fp16 = X fp16 @ W -------

__global__ __launch_bounds__(256) void k_gemm_mfma_h(const __half* __restrict__ X,
                                                     const float* __restrict__ W,
                                                     __half* __restrict__ Y) {
    __shared__ _Float16 Ah[128][40];
    __shared__ _Float16 Bh[128][40];
    __shared__ _Float16 Bl[128][40];

    const int tid = threadIdx.x;
    const int wv = tid >> 6;
    const int ln = tid & 63;
    const long rowbase = (long)blockIdx.x * 128;

    floatx4 acc[2][8];
#pragma unroll
    for (int i = 0; i < 2; ++i)
#pragma unroll
        for (int j = 0; j < 8; ++j) acc[i][j] = (floatx4)(0.f);

    for (int k0 = 0; k0 < 128; k0 += 32) {
        {
            int row = tid >> 1;
            int kh = (tid & 1) * 16;
            const __half* src = &X[(rowbase + row) * 128 + k0 + kh];
            *(half8*)&Ah[row][kh] = *(const half8*)&src[0];
            *(half8*)&Ah[row][kh + 8] = *(const half8*)&src[8];
        }
        {
            int n = tid & 127;
            int kh = (tid >> 7) * 16;
            _Float16 hi[16], lo[16];
#pragma unroll
            for (int i = 0; i < 16; ++i) {
                float v = W[(k0 + kh + i) * 128 + n];
                hi[i] = (_Float16)v;
                lo[i] = (_Float16)(v - (float)hi[i]);
            }
            *(half8*)&Bh[n][kh] = *(half8*)&hi[0];
            *(half8*)&Bh[n][kh + 8] = *(half8*)&hi[8];
            *(half8*)&Bl[n][kh] = *(half8*)&lo[0];
            *(half8*)&Bl[n][kh + 8] = *(half8*)&lo[8];
        }
        __syncthreads();

        int arow0 = wv * 32 + (ln & 15);
        int kq = (ln >> 4) * 8;
        half8 a0 = *(const half8*)&Ah[arow0][kq];
        half8 a1 = *(const half8*)&Ah[arow0 + 16][kq];
#pragma unroll
        for (int ct = 0; ct < 8; ++ct) {
            int bcol = ct * 16 + (ln & 15);
            half8 b_hi = *(const half8*)&Bh[bcol][kq];
            half8 b_lo = *(const half8*)&Bl[bcol][kq];
            acc[0][ct] = __builtin_amdgcn_mfma_f32_16x16x32_f16(a0, b_hi, acc[0][ct], 0, 0, 0);
            acc[0][ct] = __builtin_amdgcn_mfma_f32_16x16x32_f16(a0, b_lo, acc[0][ct], 0, 0, 0);
            acc[1][ct] = __builtin_amdgcn_mfma_f32_16x16x32_f16(a1, b_hi, acc[1][ct], 0, 0, 0);
            acc[1][ct] = __builtin_amdgcn_mfma_f32_16x16x32_f16(a1, b_lo, acc[1][ct], 0, 0, 0);
        }
        __syncthreads();
    }

#pragma unroll
    for (int rt = 0; rt < 2; ++rt)
#pragma unroll
        for (int ct = 0; ct < 8; ++ct)
#pragma unroll
            for (int reg = 0; reg < 4; ++reg) {
                long row = rowbase + wv * 32 + rt * 16 + (ln >> 4) * 4 + reg;
                Y[row * 128 + ct * 16 + (ln & 15)] = __float2half(acc[rt][ct][reg]);
            }
}

// ---------------- MFMA FC (fp16 A): out[Nx64] fp32 = X fp16 @ W[128x64] + b ----

__global__ __launch_bounds__(256) void k_fc_mfma_h(const __half* __restrict__ X,
                                                   const float* __restrict__ W,
                                                   const float* __restrict__ bias,
                                                   float* __restrict__ Y) {
    __shared__ _Float16 Ah[128][40];
    __shared__ _Float16 Bh[64][40];
    __shared__ _Float16 Bl[64][40];

    const int tid = threadIdx.x;
    const int wv = tid >> 6;
    const int ln = tid & 63;
    const long rowbase = (long)blockIdx.x * 128;

    floatx4 acc[2][4];
#pragma unroll
    for (int i = 0; i < 2; ++i)
#pragma unroll
        for (int j = 0; j < 4; ++j) acc[i][j] = (floatx4)(0.f);

    for (int k0 = 0; k0 < 128; k0 += 32) {
        {
            int row = tid >> 1;
            int kh = (tid & 1) * 16;
            const __half* src = &X[(rowbase + row) * 128 + k0 + kh];
            *(half8*)&Ah[row][kh] = *(const half8*)&src[0];
            *(half8*)&Ah[row][kh + 8] = *(const half8*)&src[8];
        }
        {
            int n = tid & 63;
            int kh = (tid >> 6) * 8;   // 0,8,16,24
            _Float16 hi[8], lo[8];
#pragma unroll
            for (int i = 0; i < 8; ++i) {
                float v = W[(k0 + kh + i) * 64 + n];
                hi[i] = (_Float16)v;
                lo[i] = (_Float16)(v - (float)hi[i]);
            }
            *(half8*)&Bh[n][kh] = *(half8*)&hi[0];
            *(half8*)&Bl[n][kh] = *(half8*)&lo[0];
        }
        __syncthreads();

        int arow0 = wv * 32 + (ln & 15);
        int kq = (ln >> 4) * 8;
        half8 a0 = *(const half8*)&Ah[arow0][kq];
        half8 a1 = *(const half8*)&Ah[arow0 + 16][kq];
#pragma unroll
        for (int ct = 0; ct < 4; ++ct) {
            int bcol = ct * 16 + (ln & 15);
            half8 b_hi = *(const half8*)&Bh[bcol][kq];
            half8 b_lo = *(const half8*)&Bl[bcol][kq];
            acc[0][ct] = __builtin_amdgcn_mfma_f32_16x16x32_f16(a0, b_hi, acc[0][ct], 0, 0, 0);
            acc[0][ct] = __builtin_amdgcn_mfma_f32_16x16x32_f16(a0, b_lo, acc[0][ct], 0, 0, 0);
            acc[1][ct] = __builtin_amdgcn_mfma_f32_16x16x32_f16(a1, b_hi, acc[1][ct], 0, 0, 0);
            acc[1][ct] = __builtin_amdgcn_mfma_f32_16x16x32_f16(a1, b_lo, acc[1][ct], 0, 0, 0);
        }
        __syncthreads();
    }

#pragma unroll
    for (int rt = 0; rt < 2; ++rt)
#pragma unroll
        for (int ct = 0; ct < 4; ++ct)
#pragma unroll
            for (int reg = 0; reg < 4; ++reg) {
                long row = rowbase + wv * 32 + rt * 16 + (ln >> 4) * 4 + reg;
                int col = ct * 16 + (ln & 15);
                Y[row * 64 + col] = acc[rt][ct][reg] + bias[col];
            }
}

// ---------------- CSR gather aggregation (fp16 h in/out, packed 8B edges) ------
// Proven R7 schedule: one wave per node, 64-edge coalesced batch (nontemporal),
// shfl-broadcast, 8 independent 256B row-gathers in flight into 8 accumulators.
// out[n] = relu( di*Sum_j coef'_j h[src_j] + di^2 h[n] + b ), stored fp16.

__global__ __launch_bounds__(256) void k_aggregate(const __half2* __restrict__ hlin,
                                                   const int* __restrict__ row_ptr,
                                                   const ull* __restrict__ edge8,
                                                   const float* __restrict__ dinv,
                                                   const float* __restrict__ bias,
                                                   __half2* __restrict__ out) {
    int wave = threadIdx.x >> 6;
    int lane = threadIdx.x & 63;
    int n = (blockIdx.x << 2) + wave;

    float di = dinv[n];
    float sc = di * di;

    float2 h0 = __half22float2(hlin[(size_t)n * 64 + lane]);
    float2 a0, a1, a2, a3, a4, a5, a6, a7;
    a0 = a1 = a2 = a3 = a4 = a5 = a6 = a7 = make_float2(0.f, 0.f);

    int beg = row_ptr[n];
    int end = row_ptr[n + 1];
    for (int jb = beg; jb < end; jb += 64) {
        int nload = end - jb;
        if (nload > 64) nload = 64;
        ull r = 0ULL;
        if (lane < nload) r = __builtin_nontemporal_load(&edge8[jb + lane]);
        for (int q = 0; q < nload; q += 8) {
            ull r0 = __shfl(r, q + 0), r1 = __shfl(r, q + 1);
            ull r2 = __shfl(r, q + 2), r3 = __shfl(r, q + 3);
            ull r4 = __shfl(r, q + 4), r5 = __shfl(r, q + 5);
            ull r6 = __shfl(r, q + 6), r7 = __shfl(r, q + 7);
            int s0 = (int)(r0 & 0xFFFF), s1 = (int)(r1 & 0xFFFF);
            int s2 = (int)(r2 & 0xFFFF), s3 = (int)(r3 & 0xFFFF);
            int s4 = (int)(r4 & 0xFFFF), s5 = (int)(r5 & 0xFFFF);
            int s6 = (int)(r6 & 0xFFFF), s7 = (int)(r7 & 0xFFFF);
            float c0 = __uint_as_float((unsigned int)(r0 >> 32));
            float c1 = __uint_as_float((unsigned int)(r1 >> 32));
            float c2 = __uint_as_float((unsigned int)(r2 >> 32));
            float c3 = __uint_as_float((unsigned int)(r3 >> 32));
            float c4 = __uint_as_float((unsigned int)(r4 >> 32));
            float c5 = __uint_as_float((unsigned int)(r5 >> 32));
            float c6 = __uint_as_float((unsigned int)(r6 >> 32));
            float c7 = __uint_as_float((unsigned int)(r7 >> 32));
            __half2 g0 = hlin[(size_t)s0 * 64 + lane];
            __half2 g1 = hlin[(size_t)s1 * 64 + lane];
            __half2 g2 = hlin[(size_t)s2 * 64 + lane];
            __half2 g3 = hlin[(size_t)s3 * 64 + lane];
            __half2 g4 = hlin[(size_t)s4 * 64 + lane];
            __half2 g5 = hlin[(size_t)s5 * 64 + lane];
            __half2 g6 = hlin[(size_t)s6 * 64 + lane];
            __half2 g7 = hlin[(size_t)s7 * 64 + lane];
            float2 f0 = __half22float2(g0), f1 = __half22float2(g1);
            float2 f2 = __half22float2(g2), f3 = __half22float2(g3);
            float2 f4 = __half22float2(g4), f5 = __half22float2(g5);
            float2 f6 = __half22float2(g6), f7 = __half22float2(g7);
            a0.x = fmaf(c0, f0.x, a0.x); a0.y = fmaf(c0, f0.y, a0.y);
            a1.x = fmaf(c1, f1.x, a1.x); a1.y = fmaf(c1, f1.y, a1.y);
            a2.x = fmaf(c2, f2.x, a2.x); a2.y = fmaf(c2, f2.y, a2.y);
            a3.x = fmaf(c3, f3.x, a3.x); a3.y = fmaf(c3, f3.y, a3.y);
            a4.x = fmaf(c4, f4.x, a4.x); a4.y = fmaf(c4, f4.y, a4.y);
            a5.x = fmaf(c5, f5.x, a5.x); a5.y = fmaf(c5, f5.y, a5.y);
            a6.x = fmaf(c6, f6.x, a6.x); a6.y = fmaf(c6, f6.y, a6.y);
            a7.x = fmaf(c7, f7.x, a7.x); a7.y = fmaf(c7, f7.y, a7.y);
        }
    }

    float2 sum;
    sum.x = ((a0.x + a1.x) + (a2.x + a3.x)) + ((a4.x + a5.x) + (a6.x + a7.x));
    sum.y = ((a0.y + a1.y) + (a2.y + a3.y)) + ((a4.y + a5.y) + (a6.y + a7.y));

    float2 bb = ((const float2*)bias)[lane];
    float ox = fmaxf(fmaf(di, sum.x, fmaf(sc, h0.x, bb.x)), 0.f);
    float oy = fmaxf(fmaf(di, sum.y, fmaf(sc, h0.y, bb.y)), 0.f);
    out[(size_t)n * 64 + lane] = __floats2half2_rn(ox, oy);
}

// ---------------- launch ----------------

extern "C" void kernel_launch(void* const* d_in, const int* in_sizes, int n_in,
                              void* d_out, int out_size, void* d_ws, size_t ws_size,
                              hipStream_t stream) {
    const float* x   = (const float*)d_in[0];
    const int*   ei  = (const int*)d_in[1];
    const float* ew  = (const float*)d_in[2];
    const float* W1  = (const float*)d_in[4];
    const float* b1  = (const float*)d_in[5];
    const float* W2  = (const float*)d_in[6];
    const float* b2  = (const float*)d_in[7];
    const float* fcW = (const float*)d_in[8];
    const float* fcb = (const float*)d_in[9];
    float* out = (float*)d_out;

    const int* srcArr = ei;
    const int* dstArr = ei + N_EDGES;

    char* w = (char*)d_ws;
    int* gcnt = (int*)w;               w += 256 * 4;
    int* boff = (int*)w;               w += 257 * 4;
    int* gfill = (int*)w;              w += 256 * 4;
    w += 4;
    float* dinv = (float*)w;           w += (size_t)N_NODES * 4;
    int* row_ptr = (int*)w;            w += (size_t)(N_NODES + 64) * 4;
    ull* edge8 = (ull*)w;              w += (size_t)N_EDGES * 8;
    __half* bufH = (__half*)w;         w += (size_t)N_NODES * F * 2;  // h (gather src)
    __half* bufB = (__half*)w;         w += (size_t)N_NODES * F * 2;  // agg out (fp16)
    ull* brec = (ull*)bufH;            // 8MB, dead before gemm1 writes bufH

    hipMemsetAsync(gcnt, 0, 256 * 4, stream);
    k_bcount<<<N_EDGES / 4096, 256, 0, stream>>>(dstArr, gcnt);
    k_bscan<<<1, 256, 0, stream>>>(gcnt, boff, gfill);
    k_bpart<<<N_EDGES / 4096, 256, 0, stream>>>(srcArr, dstArr, ew, gfill, brec);
    k_build<<<NBUCK, 256, 0, stream>>>(brec, boff, dinv, row_ptr, edge8);
    k_coef<<<N_EDGES / 1024, 256, 0, stream>>>(edge8, dinv);

    // layer 1: h1 fp16 = x @ W1 (hi/lo emulated fp32)
    k_gemm_mfma<<<512, 256, 0, stream>>>(x, W1, bufH);
    k_aggregate<<<N_NODES / 4, 256, 0, stream>>>((const __half2*)bufH, row_ptr, edge8,
                                                 dinv, b1, (__half2*)bufB);
    // layer 2: h2 fp16 = agg1(fp16) @ W2
    k_gemm_mfma_h<<<512, 256, 0, stream>>>(bufB, W2, bufH);
    k_aggregate<<<N_NODES / 4, 256, 0, stream>>>((const __half2*)bufH, row_ptr, edge8,
                                                 dinv, b2, (__half2*)bufB);
    // FC: out fp32 = agg2(fp16) @ fcW + fcb
    k_fc_mfma_h<<<512, 256, 0, stream>>>(bufB, fcW, fcb, out);
}

// Round 13
// 153.786 us; speedup vs baseline: 2.0263x; 1.2860x over previous
//
#include <hip/hip_runtime.h>
#include <hip/hip_fp16.h>

#define N_NODES 65536
#define N_EDGES 1048576
#define F 128
#define NBUCK 256          // dst >> 8
#define BCAP 8192          // fixed bucket capacity (mean 4096, sd ~64)

typedef unsigned long long ull;
typedef _Float16 half8 __attribute__((ext_vector_type(8)));
typedef float floatx4 __attribute__((ext_vector_type(4)));

// ---------------- bucket partition (single pass, fixed-capacity buckets) ------
// brec[b*BCAP + pos]: ew(32) | dloc(8 @ bit16) | src(16)

__global__ __launch_bounds__(256) void k_bpart(const int* __restrict__ srcArr,
                                               const int* __restrict__ dstArr,
                                               const float* __restrict__ ew,
                                               int* __restrict__ gfill,
                                               ull* __restrict__ brec) {
    __shared__ int hist[NBUCK];
    __shared__ int cur[NBUCK];
    int t = threadIdx.x;
    hist[t] = 0;
    __syncthreads();
    int base = blockIdx.x * 4096;
    int dv[16];
#pragma unroll
    for (int i = 0; i < 16; ++i) {
        dv[i] = dstArr[base + i * 256 + t];
        atomicAdd(&hist[dv[i] >> 8], 1);
    }
    __syncthreads();
    cur[t] = t * BCAP + atomicAdd(&gfill[t], hist[t]);
    __syncthreads();
#pragma unroll
    for (int i = 0; i < 16; ++i) {
        int e = base + i * 256 + t;
        int d = dv[i];
        unsigned int s = (unsigned int)srcArr[e];
        unsigned int wb = __float_as_uint(ew[e]);
        int pos = atomicAdd(&cur[d >> 8], 1);
        brec[pos] = ((ull)wb << 32) | ((ull)(d & 255) << 16) | (ull)s;
    }
}

// per-bucket CSR build: LDS hist (count<<40 | fixed-point ew-sum) -> dinv,
// local scan -> row_info[n] = (beg<<16)|deg, rank -> edge8 = ew(32)|src(16).
// edge8 shares the fixed-capacity layout (holes between buckets are fine).

__global__ __launch_bounds__(256) void k_build(const ull* __restrict__ brec,
                                               const int* __restrict__ gfill,
                                               float* __restrict__ dinv,
                                               ull* __restrict__ row_info,
                                               ull* __restrict__ edge8) {
    __shared__ ull packed[256];
    __shared__ int sc[256];
    __shared__ int cur[256];
    int t = threadIdx.x;
    int b = blockIdx.x;
    int cnt = gfill[b];
    int beg0 = b * BCAP;
    packed[t] = 0ULL;
    __syncthreads();

    for (int j = t; j < cnt; j += 256) {
        ull r = brec[beg0 + j];
        int dloc = (int)((r >> 16) & 255);
        float w = __uint_as_float((unsigned int)(r >> 32));
        ull fx = (ull)(w * 1073741824.0f);  // 2^30 fixed point
        atomicAdd(&packed[dloc], (1ULL << 40) | fx);
    }
    __syncthreads();

    ull p = packed[t];
    int c = (int)(p >> 40);
    float deg = 1.0f + (float)(p & ((1ULL << 40) - 1)) * (1.0f / 1073741824.0f);
    dinv[b * 256 + t] = rsqrtf(deg);

    sc[t] = c;
    __syncthreads();
    for (int off = 1; off < 256; off <<= 1) {
        int tv = (t >= off) ? sc[t - off] : 0;
        __syncthreads();
        sc[t] += tv;
        __syncthreads();
    }
    int excl = sc[t] - c;
    row_info[b * 256 + t] = ((ull)(beg0 + excl) << 16) | (ull)c;
    cur[t] = beg0 + excl;
    __syncthreads();

    for (int j = t; j < cnt; j += 256) {
        ull r = brec[beg0 + j];
        int dloc = (int)((r >> 16) & 255);
        int pos = atomicAdd(&cur[dloc], 1);
        edge8[pos] = (r & 0xFFFFFFFF00000000ULL) | (r & 0xFFFFULL);  // ew | src
    }
}

// ---------------- MFMA GEMM (fp32 A via hi/lo): Y = dinv ⊙ (X fp32 @ W), fp16 -

__global__ __launch_bounds__(256) void k_gemm_mfma(const float* __restrict__ X,
                                                   const float* __restrict__ W,
                                                   const float* __restrict__ dinv,
                                                   __half* __restrict__ Y) {
    __shared__ _Float16 Ah[128][40];
    __shared__ _Float16 Al[128][40];
    __shared__ _Float16 Bh[128][40];
    __shared__ _Float16 Bl[128][40];

    const int tid = threadIdx.x;
    const int wv = tid >> 6;
    const int ln = tid & 63;
    const long rowbase = (long)blockIdx.x * 128;

    floatx4 acc[2][8];
#pragma unroll
    for (int i = 0; i < 2; ++i)
#pragma unroll
        for (int j = 0; j < 8; ++j) acc[i][j] = (floatx4)(0.f);

    for (int k0 = 0; k0 < 128; k0 += 32) {
        {
            int row = tid >> 1;
            int kh = (tid & 1) * 16;
            const float* src = &X[(rowbase + row) * 128 + k0 + kh];
            _Float16 hi[16], lo[16];
#pragma unroll
            for (int i = 0; i < 16; i += 4) {
                float4 v = *(const float4*)&src[i];
                hi[i + 0] = (_Float16)v.x; lo[i + 0] = (_Float16)(v.x - (float)hi[i + 0]);
                hi[i + 1] = (_Float16)v.y; lo[i + 1] = (_Float16)(v.y - (float)hi[i + 1]);
                hi[i + 2] = (_Float16)v.z; lo[i + 2] = (_Float16)(v.z - (float)hi[i + 2]);
                hi[i + 3] = (_Float16)v.w; lo[i + 3] = (_Float16)(v.w - (float)hi[i + 3]);
            }
            *(half8*)&Ah[row][kh] = *(half8*)&hi[0];
            *(half8*)&Ah[row][kh + 8] = *(half8*)&hi[8];
            *(half8*)&Al[row][kh] = *(half8*)&lo[0];
            *(half8*)&Al[row][kh + 8] = *(half8*)&lo[8];
        }
        {
            int n = tid & 127;
            int kh = (tid >> 7) * 16;
            _Float16 hi[16], lo[16];
#pragma unroll
            for (int i = 0; i < 16; ++i) {
                float v = W[(k0 + kh + i) * 128 + n];
                hi[i] = (_Float16)v;
                lo[i] = (_Float16)(v - (float)hi[i]);
            }
            *(half8*)&Bh[n][kh] = *(half8*)&hi[0];
            *(half8*)&Bh[n][kh + 8] = *(half8*)&hi[8];
            *(half8*)&Bl[n][kh] = *(half8*)&lo[0];
            *(half8*)&Bl[n][kh + 8] = *(half8*)&lo[8];
        }
        __syncthreads();

        int arow0 = wv * 32 + (ln & 15);
        int kq = (ln >> 4) * 8;
        half8 a_hi0 = *(const half8*)&Ah[arow0][kq];
        half8 a_hi1 = *(const half8*)&Ah[arow0 + 16][kq];
        half8 a_lo0 = *(const half8*)&Al[arow0][kq];
        half8 a_lo1 = *(const half8*)&Al[arow0 + 16][kq];
#pragma unroll
        for (int ct = 0; ct < 8; ++ct) {
            int bcol = ct * 16 + (ln & 15);
            half8 b_hi = *(const half8*)&Bh[bcol][kq];
            half8 b_lo = *(const half8*)&Bl[bcol][kq];
            acc[0][ct] = __builtin_amdgcn_mfma_f32_16x16x32_f16(a_hi0, b_hi, acc[0][ct], 0, 0, 0);
            acc[0][ct] = __builtin_amdgcn_mfma_f32_16x16x32_f16(a_hi0, b_lo, acc[0][ct], 0, 0, 0);
            acc[0][ct] = __builtin_amdgcn_mfma_f32_16x16x32_f16(a_lo0, b_hi, acc[0][ct], 0, 0, 0);
            acc[1][ct] = __builtin_amdgcn_mfma_f32_16x16x32_f16(a_hi1, b_hi, acc[1][ct], 0, 0, 0);
            acc[1][ct] = __builtin_amdgcn_mfma_f32_16x16x32_f16(a_hi1, b_lo, acc[1][ct], 0, 0, 0);
            acc[1][ct] = __builtin_amdgcn_mfma_f32_16x16x32_f16(a_lo1, b_hi, acc[1][ct], 0, 0, 0);
        }
        __syncthreads();
    }

#pragma unroll
    for (int rt = 0; rt < 2; ++rt)
#pragma unroll
        for (int reg = 0; reg < 4; ++reg) {
            long row = rowbase + wv * 32 + rt * 16 + (ln >> 4) * 4 + reg;
            float dv = dinv[row];
#pragma unroll
            for (int ct = 0; ct < 8; ++ct)
                Y[row * 128 + ct * 16 + (ln & 15)] = __float2half(acc[rt][ct][reg] * dv);
        }
}

// ---------------- MFMA GEMM (fp16 A): Y = dinv ⊙ (X fp16 @ W), fp16 -----------

__global__ __launch_bounds__(256) void k_gemm_mfma_h(const __half* __restrict__ X,
                                                     const float* __restrict__ W,
                                                     const float* __restrict__ dinv,
                                                     __half* __restrict__ Y) {
    __shared__ _Float16 Ah[128][40];
    __shared__ _Float16 Bh[128][40];
    __shared__ _Float16 Bl[128][40];

    const int tid = threadIdx.x;
    const int wv = tid >> 6;
    const int ln = tid & 63;
    const long rowbase = (long)blockIdx.x * 128;

    floatx4 acc[2][8];
#pragma unroll
    for (int i = 0; i < 2; ++i)
#pragma unroll
        for (int j = 0; j < 8; ++j) acc[i][j] = (floatx4)(0.f);

    for (int k0 = 0; k0 < 128; k0 += 32) {
        {
            int row = tid >> 1;
            int kh = (tid & 1) * 16;
            const __half* src = &X[(rowbase + row) * 128 + k0 + kh];
            *(half8*)&Ah[row][kh] = *(const half8*)&src[0];
            *(half8*)&Ah[row][kh + 8] = *(const half8*)&src[8];
        }
        {
            int n = tid & 127;
            int kh = (tid >> 7) * 16;
            _Float16 hi[16], lo[16];
#pragma unroll
            for (int i = 0; i < 16; ++i) {
                float v = W[(k0 + kh + i) * 128 + n];
                hi[i] = (_Float16)v;
                lo[i] = (_Float16)(v - (float)hi[i]);
            }
            *(half8*)&Bh[n][kh] = *(half8*)&hi[0];
            *(half8*)&Bh[n][kh + 8] = *(half8*)&hi[8];
            *(half8*)&Bl[n][kh] = *(half8*)&lo[0];
            *(half8*)&Bl[n][kh + 8] = *(half8*)&lo[8];
        }
        __syncthreads();

        int arow0 = wv * 32 + (ln & 15);
        int kq = (ln >> 4) * 8;
        half8 a0 = *(const half8*)&Ah[arow0][kq];
        half8 a1 = *(const half8*)&Ah[arow0 + 16][kq];
#pragma unroll
        for (int ct = 0; ct < 8; ++ct) {
            int bcol = ct * 16 + (ln & 15);
            half8 b_hi = *(const half8*)&Bh[bcol][kq];
            half8 b_lo = *(const half8*)&Bl[bcol][kq];
            acc[0][ct] = __builtin_amdgcn_mfma_f32_16x16x32_f16(a0, b_hi, acc[0][ct], 0, 0, 0);
            acc[0][ct] = __builtin_amdgcn_mfma_f32_16x16x32_f16(a0, b_lo, acc[0][ct], 0, 0, 0);
            acc[1][ct] = __builtin_amdgcn_mfma_f32_16x16x32_f16(a1, b_hi, acc[1][ct], 0, 0, 0);
            acc[1][ct] = __builtin_amdgcn_mfma_f32_16x16x32_f16(a1, b_lo, acc[1][ct], 0, 0, 0);
        }
        __syncthreads();
    }

#pragma unroll
    for (int rt = 0; rt < 2; ++rt)
#pragma unroll
        for (int reg = 0; reg < 4; ++reg) {
            long row = rowbase + wv * 32 + rt * 16 + (ln >> 4) * 4 + reg;
            float dv = dinv[row];
#pragma unroll
            for (int ct = 0; ct < 8; ++ct)
                Y[row * 128 + ct * 16 + (ln & 15)] = __float2half(acc[rt][ct][reg] * dv);
        }
}

// ---------------- MFMA FC (fp16 A): out[Nx64] fp32 = X fp16 @ W[128x64] + b ----

__global__ __launch_bounds__(256) void k_fc_mfma_h(const __half* __restrict__ X,
                                                   const float* __restrict__ W,
                                                   const float* __restrict__ bias,
                                                   float* __restrict__ Y) {
    __shared__ _Float16 Ah[128][40];
    __shared__ _Float16 Bh[64][40];
    __shared__ _Float16 Bl[64][40];

    const int tid = threadIdx.x;
    const int wv = tid >> 6;
    const int ln = tid & 63;
    const long rowbase = (long)blockIdx.x * 128;

    floatx4 acc[2][4];
#pragma unroll
    for (int i = 0; i < 2; ++i)
#pragma unroll
        for (int j = 0; j < 4; ++j) acc[i][j] = (floatx4)(0.f);

    for (int k0 = 0; k0 < 128; k0 += 32) {
        {
            int row = tid >> 1;
            int kh = (tid & 1) * 16;
            const __half* src = &X[(rowbase + row) * 128 + k0 + kh];
            *(half8*)&Ah[row][kh] = *(const half8*)&src[0];
            *(half8*)&Ah[row][kh + 8] = *(const half8*)&src[8];
        }
        {
            int n = tid & 63;
            int kh = (tid >> 6) * 8;   // 0,8,16,24
            _Float16 hi[8], lo[8];
#pragma unroll
            for (int i = 0; i < 8; ++i) {
                float v = W[(k0 + kh + i) * 64 + n];
                hi[i] = (_Float16)v;
                lo[i] = (_Float16)(v - (float)hi[i]);
            }
            *(half8*)&Bh[n][kh] = *(half8*)&hi[0];
            *(half8*)&Bl[n][kh] = *(half8*)&lo[0];
        }
        __syncthreads();

        int arow0 = wv * 32 + (ln & 15);
        int kq = (ln >> 4) * 8;
        half8 a0 = *(const half8*)&Ah[arow0][kq];
        half8 a1 = *(const half8*)&Ah[arow0 + 16][kq];
#pragma unroll
        for (int ct = 0; ct < 4; ++ct) {
            int bcol = ct * 16 + (ln & 15);
            half8 b_hi = *(const half8*)&Bh[bcol][kq];
            half8 b_lo = *(const half8*)&Bl[bcol][kq];
            acc[0][ct] = __builtin_amdgcn_mfma_f32_16x16x32_f16(a0, b_hi, acc[0][ct], 0, 0, 0);
            acc[0][ct] = __builtin_amdgcn_mfma_f32_16x16x32_f16(a0, b_lo, acc[0][ct], 0, 0, 0);
            acc[1][ct] = __builtin_amdgcn_mfma_f32_16x16x32_f16(a1, b_hi, acc[1][ct], 0, 0, 0);
            acc[1][ct] = __builtin_amdgcn_mfma_f32_16x16x32_f16(a1, b_lo, acc[1][ct], 0, 0, 0);
        }
        __syncthreads();
    }

#pragma unroll
    for (int rt = 0; rt < 2; ++rt)
#pragma unroll
        for (int ct = 0; ct < 4; ++ct)
#pragma unroll
            for (int reg = 0; reg < 4; ++reg) {
                long row = rowbase + wv * 32 + rt * 16 + (ln >> 4) * 4 + reg;
                int col = ct * 16 + (ln & 15);
                Y[row * 64 + col] = acc[rt][ct][reg] + bias[col];
            }
}

// ---------------- CSR gather aggregation (h' = dinv*h fp16, raw-ew edges) ------
// out[n] = relu( di*(Σ_j ew_j h'[src_j] + h'[n]) + b ), stored fp16 (plain act).
// One wave per node, 64-edge NT batch, 8 independent 256B gathers in flight.

__global__ __launch_bounds__(256) void k_aggregate(const __half2* __restrict__ hlin,
                                                   const ull* __restrict__ row_info,
                                                   const ull* __restrict__ edge8,
                                                   const float* __restrict__ dinv,
                                                   const float* __restrict__ bias,
                                                   __half2* __restrict__ out) {
    int wave = threadIdx.x >> 6;
    int lane = threadIdx.x & 63;
    int n = (blockIdx.x << 2) + wave;

    float di = dinv[n];
    ull info = row_info[n];
    int beg = (int)(info >> 16);
    int end = beg + (int)(info & 0xFFFF);

    float2 h0 = __half22float2(hlin[(size_t)n * 64 + lane]);
    float2 a0, a1, a2, a3, a4, a5, a6, a7;
    a0 = a1 = a2 = a3 = a4 = a5 = a6 = a7 = make_float2(0.f, 0.f);

    for (int jb = beg; jb < end; jb += 64) {
        int nload = end - jb;
        if (nload > 64) nload = 64;
        ull r = 0ULL;
        if (lane < nload) r = __builtin_nontemporal_load(&edge8[jb + lane]);
        for (int q = 0; q < nload; q += 8) {
            ull r0 = __shfl(r, q + 0), r1 = __shfl(r, q + 1);
            ull r2 = __shfl(r, q + 2), r3 = __shfl(r, q + 3);
            ull r4 = __shfl(r, q + 4), r5 = __shfl(r, q + 5);
            ull r6 = __shfl(r, q + 6), r7 = __shfl(r, q + 7);
            int s0 = (int)(r0 & 0xFFFF), s1 = (int)(r1 & 0xFFFF);
            int s2 = (int)(r2 & 0xFFFF), s3 = (int)(r3 & 0xFFFF);
            int s4 = (int)(r4 & 0xFFFF), s5 = (int)(r5 & 0xFFFF);
            int s6 = (int)(r6 & 0xFFFF), s7 = (int)(r7 & 0xFFFF);
            float c0 = __uint_as_float((unsigned int)(r0 >> 32));
            float c1 = __uint_as_float((unsigned int)(r1 >> 32));
            float c2 = __uint_as_float((unsigned int)(r2 >> 32));
            float c3 = __uint_as_float((unsigned int)(r3 >> 32));
            float c4 = __uint_as_float((unsigned int)(r4 >> 32));
            float c5 = __uint_as_float((unsigned int)(r5 >> 32));
            float c6 = __uint_as_float((unsigned int)(r6 >> 32));
            float c7 = __uint_as_float((unsigned int)(r7 >> 32));
            __half2 g0 = hlin[(size_t)s0 * 64 + lane];
            __half2 g1 = hlin[(size_t)s1 * 64 + lane];
            __half2 g2 = hlin[(size_t)s2 * 64 + lane];
            __half2 g3 = hlin[(size_t)s3 * 64 + lane];
            __half2 g4 = hlin[(size_t)s4 * 64 + lane];
            __half2 g5 = hlin[(size_t)s5 * 64 + lane];
            __half2 g6 = hlin[(size_t)s6 * 64 + lane];
            __half2 g7 = hlin[(size_t)s7 * 64 + lane];
            float2 f0 = __half22float2(g0), f1 = __half22float2(g1);
            float2 f2 = __half22float2(g2), f3 = __half22float2(g3);
            float2 f4 = __half22float2(g4), f5 = __half22float2(g5);
            float2 f6 = __half22float2(g6), f7 = __half22float2(g7);
            a0.x = fmaf(c0, f0.x, a0.x); a0.y = fmaf(c0, f0.y, a0.y);
            a1.x = fmaf(c1, f1.x, a1.x); a1.y = fmaf(c1, f1.y, a1.y);
            a2.x = fmaf(c2, f2.x, a2.x); a2.y = fmaf(c2, f2.y, a2.y);
            a3.x = fmaf(c3, f3.x, a3.x); a3.y = fmaf(c3, f3.y, a3.y);
            a4.x = fmaf(c4, f4.x, a4.x); a4.y = fmaf(c4, f4.y, a4.y);
            a5.x = fmaf(c5, f5.x, a5.x); a5.y = fmaf(c5, f5.y, a5.y);
            a6.x = fmaf(c6, f6.x, a6.x); a6.y = fmaf(c6, f6.y, a6.y);
            a7.x = fmaf(c7, f7.x, a7.x); a7.y = fmaf(c7, f7.y, a7.y);
        }
    }

    float2 sum;
    sum.x = ((a0.x + a1.x) + (a2.x + a3.x)) + ((a4.x + a5.x) + (a6.x + a7.x));
    sum.y = ((a0.y + a1.y) + (a2.y + a3.y)) + ((a4.y + a5.y) + (a6.y + a7.y));

    float2 bb = ((const float2*)bias)[lane];
    float ox = fmaxf(fmaf(di, sum.x + h0.x, bb.x), 0.f);
    float oy = fmaxf(fmaf(di, sum.y + h0.y, bb.y), 0.f);
    out[(size_t)n * 64 + lane] = __floats2half2_rn(ox, oy);
}

// ---------------- launch ----------------

extern "C" void kernel_launch(void* const* d_in, const int* in_sizes, int n_in,
                              void* d_out, int out_size, void* d_ws, size_t ws_size,
                              hipStream_t stream) {
    const float* x   = (const float*)d_in[0];
    const int*   ei  = (const int*)d_in[1];
    const float* ew  = (const float*)d_in[2];
    const float* W1  = (const float*)d_in[4];
    const float* b1  = (const float*)d_in[5];
    const float* W2  = (const float*)d_in[6];
    const float* b2  = (const float*)d_in[7];
    const float* fcW = (const float*)d_in[8];
    const float* fcb = (const float*)d_in[9];
    float* out = (float*)d_out;

    const int* srcArr = ei;
    const int* dstArr = ei + N_EDGES;

    char* w = (char*)d_ws;
    int* gfill = (int*)w;              w += 256 * 4;
    float* dinv = (float*)w;           w += (size_t)N_NODES * 4;
    ull* row_info = (ull*)w;           w += (size_t)N_NODES * 8;
    ull* edge8 = (ull*)w;              w += (size_t)NBUCK * BCAP * 8;   // 16MB
    __half* bufH = (__half*)w;         w += (size_t)N_NODES * F * 2;    // 16MB h'
    __half* bufB = (__half*)w;         w += (size_t)N_NODES * F * 2;    // 16MB act
    ull* brec = (ull*)bufH;            // 16MB, dead before gemm1 writes bufH

    hipMemsetAsync(gfill, 0, 256 * 4, stream);
    k_bpart<<<N_EDGES / 4096, 256, 0, stream>>>(srcArr, dstArr, ew, gfill, brec);
    k_build<<<NBUCK, 256, 0, stream>>>(brec, gfill, dinv, row_info, edge8);

    // layer 1: h1' = dinv ⊙ (x @ W1)
    k_gemm_mfma<<<512, 256, 0, stream>>>(x, W1, dinv, bufH);
    k_aggregate<<<N_NODES / 4, 256, 0, stream>>>((const __half2*)bufH, row_info, edge8,
                                                 dinv, b1, (__half2*)bufB);
    // layer 2: h2' = dinv ⊙ (agg1 @ W2)
    k_gemm_mfma_h<<<512, 256, 0, stream>>>(bufB, W2, dinv, bufH);
    k_aggregate<<<N_NODES / 4, 256, 0, stream>>>((const __half2*)bufH, row_info, edge8,
                                                 dinv, b2, (__half2*)bufB);
    // FC: out fp32 = agg2 @ fcW + fcb
    k_fc_mfma_h<<<512, 256, 0, stream>>>(bufB, fcW, fcb, out);
}